// Round 12
// baseline (265.064 us; speedup 1.0000x reference)
//
#include <hip/hip_runtime.h>
#include <math.h>

#define BB 2
#define VV 768
#define HID 128
#define NH 8
#define HD 16

// Edge stream split into 4 quarters of 2048 waves; each wave owns a
// contiguous 72KB run (72 row-pairs). Quarter k covers flat (b,v) mask rows
// [k*384, (k+1)*384): k=0 -> b0 v<384, k=1 -> b0 v>=384, k=2 -> b1 v<384,
// k=3 -> b1 v>=384.
#define EQ_BLOCKS 512                 // edge blocks per quarter (4 waves each)
#define QKV_BLOCKS 768
#define ATT_BLOCKS 384                // attn blocks per quarter (4 wave-tasks)
#define PAIRS_PER_WAVE 72

// ---------------------------------------------------------------------------
// Edge-stream wave body (round-5 proven pattern): wave w owns pairs
// [w*72,(w+1)*72), 1KB each; lane l reads float4 l; half-wave xor reduce.
// ---------------------------------------------------------------------------
__device__ __forceinline__ void edge_wave(const float* __restrict__ eg,
                                          float* __restrict__ mask,
                                          int w, int l) {
    const float4* eg4 = (const float4*)eg;
    const size_t wbase = (size_t)w * (PAIRS_PER_WAVE * 64);
#pragma unroll 4
    for (int it = 0; it < PAIRS_PER_WAVE; ++it) {
        float4 v = eg4[wbase + it * 64 + l];
        float s = (v.x + v.y) + (v.z + v.w);
        s += __shfl_xor(s, 1);
        s += __shfl_xor(s, 2);
        s += __shfl_xor(s, 4);
        s += __shfl_xor(s, 8);
        s += __shfl_xor(s, 16);
        if ((l & 31) == 0) {
            const int p = w * PAIRS_PER_WAVE + it;
            mask[p * 2 + (l >> 5)] = s * (1.0f / 128.0f);
        }
    }
}

// ---------------------------------------------------------------------------
// Attention wave body (round-5 proven 2-row-per-wave), parameterized by
// (b, vlo): task gw in [0,1536): h = gw/192, prl = gw%192, rows q0=vlo+2*prl.
// sc = this wave's 2x768 score scratch in LDS.
// ---------------------------------------------------------------------------
__device__ __forceinline__ void attn_wave(const float* __restrict__ qh,
                                          const float* __restrict__ kh,
                                          const float* __restrict__ vh,
                                          const float* __restrict__ mask,
                                          float* __restrict__ att,
                                          float* sc,   // [2][VV]
                                          int gw, int b, int vlo, int lane) {
    const int h   = gw / 192;
    const int prl = gw % 192;
    const int bh  = b * NH + h;
    const int q0i = vlo + 2 * prl, q1i = q0i + 1;

    const float4* qp0 = (const float4*)(qh + ((size_t)bh * VV + q0i) * HD);
    const float4 qa0 = qp0[0], qa1 = qp0[1], qa2 = qp0[2], qa3 = qp0[3];
    const float4* qp1 = (const float4*)(qh + ((size_t)bh * VV + q1i) * HD);
    const float4 qb0 = qp1[0], qb1 = qp1[1], qb2 = qp1[2], qb3 = qp1[3];

    const float* mrow0 = mask + ((size_t)b * VV + q0i) * VV;
    const float* mrow1 = mrow0 + VV;
    const float* kbase = kh + (size_t)bh * VV * HD;
    const float* vbase = vh + (size_t)bh * VV * HD;

    float m0 = -INFINITY, m1 = -INFINITY;
#pragma unroll
    for (int t = 0; t < VV / 64; ++t) {
        const int j = lane + 64 * t;
        const float4* kp = (const float4*)(kbase + j * HD);
        float4 k0 = kp[0], k1 = kp[1], k2 = kp[2], k3 = kp[3];
        float d0 = qa0.x * k0.x + qa0.y * k0.y + qa0.z * k0.z + qa0.w * k0.w
                 + qa1.x * k1.x + qa1.y * k1.y + qa1.z * k1.z + qa1.w * k1.w
                 + qa2.x * k2.x + qa2.y * k2.y + qa2.z * k2.z + qa2.w * k2.w
                 + qa3.x * k3.x + qa3.y * k3.y + qa3.z * k3.z + qa3.w * k3.w;
        float d1 = qb0.x * k0.x + qb0.y * k0.y + qb0.z * k0.z + qb0.w * k0.w
                 + qb1.x * k1.x + qb1.y * k1.y + qb1.z * k1.z + qb1.w * k1.w
                 + qb2.x * k2.x + qb2.y * k2.y + qb2.z * k2.z + qb2.w * k2.w
                 + qb3.x * k3.x + qb3.y * k3.y + qb3.z * k3.z + qb3.w * k3.w;
        float s0 = d0 * 0.25f * mrow0[j];
        float s1 = d1 * 0.25f * mrow1[j];
        sc[j]      = s0;
        sc[VV + j] = s1;
        m0 = fmaxf(m0, s0);
        m1 = fmaxf(m1, s1);
    }
#pragma unroll
    for (int off = 1; off < 64; off <<= 1) {
        m0 = fmaxf(m0, __shfl_xor(m0, off));
        m1 = fmaxf(m1, __shfl_xor(m1, off));
    }

    float sum0 = 0.f, sum1 = 0.f;
    float acc0[HD], acc1[HD];
#pragma unroll
    for (int d = 0; d < HD; ++d) { acc0[d] = 0.f; acc1[d] = 0.f; }
#pragma unroll
    for (int t = 0; t < VV / 64; ++t) {
        const int j = lane + 64 * t;
        float e0 = __expf(sc[j] - m0);
        float e1 = __expf(sc[VV + j] - m1);
        sum0 += e0;
        sum1 += e1;
        const float4* vp = (const float4*)(vbase + j * HD);
        float4 v0 = vp[0], v1 = vp[1], v2 = vp[2], v3 = vp[3];
        acc0[0]  += e0 * v0.x; acc0[1]  += e0 * v0.y; acc0[2]  += e0 * v0.z; acc0[3]  += e0 * v0.w;
        acc0[4]  += e0 * v1.x; acc0[5]  += e0 * v1.y; acc0[6]  += e0 * v1.z; acc0[7]  += e0 * v1.w;
        acc0[8]  += e0 * v2.x; acc0[9]  += e0 * v2.y; acc0[10] += e0 * v2.z; acc0[11] += e0 * v2.w;
        acc0[12] += e0 * v3.x; acc0[13] += e0 * v3.y; acc0[14] += e0 * v3.z; acc0[15] += e0 * v3.w;
        acc1[0]  += e1 * v0.x; acc1[1]  += e1 * v0.y; acc1[2]  += e1 * v0.z; acc1[3]  += e1 * v0.w;
        acc1[4]  += e1 * v1.x; acc1[5]  += e1 * v1.y; acc1[6]  += e1 * v1.z; acc1[7]  += e1 * v1.w;
        acc1[8]  += e1 * v2.x; acc1[9]  += e1 * v2.y; acc1[10] += e1 * v2.z; acc1[11] += e1 * v2.w;
        acc1[12] += e1 * v3.x; acc1[13] += e1 * v3.y; acc1[14] += e1 * v3.z; acc1[15] += e1 * v3.w;
    }
#pragma unroll
    for (int off = 1; off < 64; off <<= 1) {
        sum0 += __shfl_xor(sum0, off);
        sum1 += __shfl_xor(sum1, off);
    }

#pragma unroll
    for (int i = 0; i < 8; ++i) {
        float sa = (lane & 1) ? acc0[i] : acc0[i + 8];
        float ra = __shfl_xor(sa, 1);
        acc0[i] = ((lane & 1) ? acc0[i + 8] : acc0[i]) + ra;
        float sb = (lane & 1) ? acc1[i] : acc1[i + 8];
        float rb = __shfl_xor(sb, 1);
        acc1[i] = ((lane & 1) ? acc1[i + 8] : acc1[i]) + rb;
    }
#pragma unroll
    for (int i = 0; i < 4; ++i) {
        float sa = (lane & 2) ? acc0[i] : acc0[i + 4];
        float ra = __shfl_xor(sa, 2);
        acc0[i] = ((lane & 2) ? acc0[i + 4] : acc0[i]) + ra;
        float sb = (lane & 2) ? acc1[i] : acc1[i + 4];
        float rb = __shfl_xor(sb, 2);
        acc1[i] = ((lane & 2) ? acc1[i + 4] : acc1[i]) + rb;
    }
#pragma unroll
    for (int i = 0; i < 2; ++i) {
        float sa = (lane & 4) ? acc0[i] : acc0[i + 2];
        float ra = __shfl_xor(sa, 4);
        acc0[i] = ((lane & 4) ? acc0[i + 2] : acc0[i]) + ra;
        float sb = (lane & 4) ? acc1[i] : acc1[i + 2];
        float rb = __shfl_xor(sb, 4);
        acc1[i] = ((lane & 4) ? acc1[i + 2] : acc1[i]) + rb;
    }
    {
        float sa = (lane & 8) ? acc0[0] : acc0[1];
        float ra = __shfl_xor(sa, 8);
        acc0[0] = ((lane & 8) ? acc0[1] : acc0[0]) + ra;
        float sb = (lane & 8) ? acc1[0] : acc1[1];
        float rb = __shfl_xor(sb, 8);
        acc1[0] = ((lane & 8) ? acc1[1] : acc1[0]) + rb;
    }
    acc0[0] += __shfl_xor(acc0[0], 16);
    acc0[0] += __shfl_xor(acc0[0], 32);
    acc1[0] += __shfl_xor(acc1[0], 16);
    acc1[0] += __shfl_xor(acc1[0], 32);

    const int d = ((lane & 1) << 3) | ((lane & 2) << 1) | ((lane & 4) >> 1) | ((lane & 8) >> 3);
    if (lane < HD) {
        att[((size_t)b * VV + q0i) * HID + h * HD + d] = acc0[0] / sum0;
        att[((size_t)b * VV + q1i) * HID + h * HD + d] = acc1[0] / sum1;
    }
}

// ---------------------------------------------------------------------------
// Out-projection body: 256 threads = 2 rows (row = off + 2*bidx + half).
// ---------------------------------------------------------------------------
__device__ __forceinline__ void outproj2_body(const float* __restrict__ att,
                                              const float* __restrict__ Wo,
                                              const float* __restrict__ bo,
                                              float* __restrict__ out,
                                              float* xs,  // [2][HID] LDS
                                              int row0) {
    const int half = threadIdx.x >> 7;
    const int c    = threadIdx.x & 127;
    const int row  = row0 + half;
    xs[half * HID + c] = att[(size_t)row * HID + c];
    __syncthreads();
    const float4* a4 = (const float4*)(xs + half * HID);
    const float4* w4 = (const float4*)(Wo + c * HID);
    float a = 0.f;
#pragma unroll
    for (int k4 = 0; k4 < HID / 4; ++k4) {
        float4 xv = a4[k4];
        float4 wv = w4[k4];
        a += xv.x * wv.x + xv.y * wv.y + xv.z * wv.z + xv.w * wv.w;
    }
    out[(size_t)row * HID + c] = a + bo[c];
}

// ---------------------------------------------------------------------------
// D1: edge quarter 0 (blocks [0,512)) + QKV projection (blocks [512,1280)).
// ---------------------------------------------------------------------------
__global__ __launch_bounds__(256) void k_edge_qkv(
    const float* __restrict__ x, const float* __restrict__ eg,
    const float* __restrict__ Wq, const float* __restrict__ bq,
    const float* __restrict__ Wk, const float* __restrict__ bk,
    const float* __restrict__ Wv, const float* __restrict__ bv,
    float* __restrict__ qh, float* __restrict__ kh, float* __restrict__ vh,
    float* __restrict__ mask) {
    __shared__ float xs[2][HID];
    const int lane = threadIdx.x & 63;
    const int wid  = threadIdx.x >> 6;
    if (blockIdx.x < EQ_BLOCKS) {
        edge_wave(eg, mask, blockIdx.x * 4 + wid, lane);
    } else {
        const int half = threadIdx.x >> 7;
        const int c    = threadIdx.x & 127;
        const int row  = (blockIdx.x - EQ_BLOCKS) * 2 + half;  // 0..1535
        xs[half][c] = x[row * HID + c];
        __syncthreads();
        const float4* xs4 = (const float4*)xs[half];
        const float4* wq4 = (const float4*)(Wq + c * HID);
        const float4* wk4 = (const float4*)(Wk + c * HID);
        const float4* wv4 = (const float4*)(Wv + c * HID);
        float aq = 0.f, ak = 0.f, av = 0.f;
#pragma unroll
        for (int k4 = 0; k4 < HID / 4; ++k4) {
            float4 xv = xs4[k4];
            float4 a = wq4[k4];
            aq += xv.x * a.x + xv.y * a.y + xv.z * a.z + xv.w * a.w;
            float4 bv2 = wk4[k4];
            ak += xv.x * bv2.x + xv.y * bv2.y + xv.z * bv2.z + xv.w * bv2.w;
            float4 cv = wv4[k4];
            av += xv.x * cv.x + xv.y * cv.y + xv.z * cv.z + xv.w * cv.w;
        }
        const int b = row / VV, vi = row - b * VV;
        const int idx = ((b * NH + (c >> 4)) * VV + vi) * HD + (c & 15);
        qh[idx] = aq + bq[c];
        kh[idx] = ak + bk[c];
        vh[idx] = av + bv[c];
    }
}

// ---------------------------------------------------------------------------
// D2-D4: edge quarter (blocks [0,512), w offset) + attn for the previous
// quarter (blocks [512,896), fixed (b, vlo)). mask is non-const here: the
// edge waves WRITE it (quarter k) while attn waves READ quarter k-1 (written
// by the previous dispatch).
// ---------------------------------------------------------------------------
__global__ __launch_bounds__(256) void k_edge_attn(
    const float* __restrict__ eg,
    const float* __restrict__ qh, const float* __restrict__ kh,
    const float* __restrict__ vh, float* __restrict__ mask,
    float* __restrict__ att, int w_off, int ab, int avlo) {
    __shared__ float sc[4][2][VV];                 // 24 KB
    const int lane = threadIdx.x & 63;
    const int wid  = threadIdx.x >> 6;
    if (blockIdx.x < EQ_BLOCKS) {
        edge_wave(eg, mask, w_off + blockIdx.x * 4 + wid, lane);
    } else {
        const int gw = (blockIdx.x - EQ_BLOCKS) * 4 + wid;   // 0..1535
        attn_wave(qh, kh, vh, mask, att, &sc[wid][0][0], gw, ab, avlo, lane);
    }
}

// ---------------------------------------------------------------------------
// D5: attn quarter 3 (blocks [0,384)) + outproj rows [0,1152) (blocks
// [384,960), 2 rows each).
// ---------------------------------------------------------------------------
__global__ __launch_bounds__(256) void k_attn_outproj(
    const float* __restrict__ qh, const float* __restrict__ kh,
    const float* __restrict__ vh, const float* __restrict__ mask,
    float* __restrict__ att,
    const float* __restrict__ Wo, const float* __restrict__ bo,
    float* __restrict__ out) {
    __shared__ float sc[4][2][VV];                 // 24 KB (union w/ xs use)
    const int lane = threadIdx.x & 63;
    const int wid  = threadIdx.x >> 6;
    if (blockIdx.x < ATT_BLOCKS) {
        const int gw = blockIdx.x * 4 + wid;                 // 0..1535
        attn_wave(qh, kh, vh, mask, att, &sc[wid][0][0], gw, 1, 384, lane);
    } else {
        outproj2_body(att, Wo, bo, out, &sc[0][0][0], (blockIdx.x - ATT_BLOCKS) * 2);
    }
}

// ---------------------------------------------------------------------------
// D6: outproj rows [1152,1536): 192 blocks, 2 rows each.
// ---------------------------------------------------------------------------
__global__ __launch_bounds__(256) void k_outproj_tail(
    const float* __restrict__ att, const float* __restrict__ Wo,
    const float* __restrict__ bo, float* __restrict__ out) {
    __shared__ float xs[2][HID];
    outproj2_body(att, Wo, bo, out, &xs[0][0], 1152 + blockIdx.x * 2);
}

extern "C" void kernel_launch(void* const* d_in, const int* in_sizes, int n_in,
                              void* d_out, int out_size, void* d_ws, size_t ws_size,
                              hipStream_t stream) {
    const float* x  = (const float*)d_in[0];
    const float* eg = (const float*)d_in[1];
    const float* Wq = (const float*)d_in[2];
    const float* bq = (const float*)d_in[3];
    const float* Wk = (const float*)d_in[4];
    const float* bk = (const float*)d_in[5];
    const float* Wv = (const float*)d_in[6];
    const float* bv = (const float*)d_in[7];
    const float* Wo = (const float*)d_in[8];
    const float* bo = (const float*)d_in[9];
    float* out = (float*)d_out;

    float* ws   = (float*)d_ws;
    float* mask = ws;                                        // B*V*V
    float* qh   = mask + (size_t)BB * VV * VV;               // B*V*HID each
    float* kh   = qh + (size_t)BB * VV * HID;
    float* vh   = kh + (size_t)BB * VV * HID;
    float* att  = vh + (size_t)BB * VV * HID;

    // D1: stream Q0 + QKV
    hipLaunchKernelGGL(k_edge_qkv, dim3(EQ_BLOCKS + QKV_BLOCKS), dim3(256), 0, stream,
                       x, eg, Wq, bq, Wk, bk, Wv, bv, qh, kh, vh, mask);
    // D2: stream Q1 + attn Q0 (b=0, v<384)
    hipLaunchKernelGGL(k_edge_attn, dim3(EQ_BLOCKS + ATT_BLOCKS), dim3(256), 0, stream,
                       eg, qh, kh, vh, mask, att, 2048, 0, 0);
    // D3: stream Q2 + attn Q1 (b=0, v>=384)
    hipLaunchKernelGGL(k_edge_attn, dim3(EQ_BLOCKS + ATT_BLOCKS), dim3(256), 0, stream,
                       eg, qh, kh, vh, mask, att, 4096, 0, 384);
    // D4: stream Q3 + attn Q2 (b=1, v<384)
    hipLaunchKernelGGL(k_edge_attn, dim3(EQ_BLOCKS + ATT_BLOCKS), dim3(256), 0, stream,
                       eg, qh, kh, vh, mask, att, 6144, 1, 0);
    // D5: attn Q3 (b=1, v>=384) + outproj rows [0,1152)
    hipLaunchKernelGGL(k_attn_outproj, dim3(ATT_BLOCKS + 576), dim3(256), 0, stream,
                       qh, kh, vh, mask, att, Wo, bo, out);
    // D6: outproj rows [1152,1536)
    hipLaunchKernelGGL(k_outproj_tail, dim3(192), dim3(256), 0, stream,
                       att, Wo, bo, out);
}

// Round 13
// 219.076 us; speedup vs baseline: 1.2099x; 1.2099x over previous
//
#include <hip/hip_runtime.h>
#include <math.h>

#define BB 2
#define VV 768
#define HID 128
#define NH 8
#define HD 16

#define QKV_BLOCKS 768                    // 2 x-rows per block -> 1536 rows
#define EDGE_BLOCKS 2048
#define EDGE_WAVES (EDGE_BLOCKS * 4)      // 8192 waves
#define NPAIR (BB * VV * VV / 2)          // 589824 row-pairs (1KB each)
#define EDGE_ITERS (NPAIR / EDGE_WAVES)   // 72 exactly

// ---------------------------------------------------------------------------
// ROUND-5 REVERT (session best: 219.5us). Kernel 1 (fused): blocks
// [0, QKV_BLOCKS) = QKV projection (head-major out); blocks [QKV_BLOCKS, ...)
// stream the 604 MB edge_gate -> edge_mask. Each edge wave owns a CONTIGUOUS
// 72 KB run; lane l reads float4 at byte l*16 of each 1 KB window (2 rows);
// half-wave xor reduce. Low VGPR (32) + 1KB LDS -> full streaming occupancy.
// Cold-read wall ~3.1 TB/s is the binding constraint (6 read-path structures
// all cap there: strided / NT / contiguous / row-per-lane / sc0-asm / LDS-DMA).
// ---------------------------------------------------------------------------
__global__ __launch_bounds__(256) void fused_qkv_edgemean(
    const float* __restrict__ x, const float* __restrict__ eg,
    const float* __restrict__ Wq, const float* __restrict__ bq,
    const float* __restrict__ Wk, const float* __restrict__ bk,
    const float* __restrict__ Wv, const float* __restrict__ bv,
    float* __restrict__ qh, float* __restrict__ kh, float* __restrict__ vh,
    float* __restrict__ mask) {
    __shared__ float xs[2][HID];
    if (blockIdx.x < QKV_BLOCKS) {
        const int half = threadIdx.x >> 7;       // 0/1 -> which row
        const int c    = threadIdx.x & 127;      // output column = h*HD+d
        const int row  = blockIdx.x * 2 + half;  // b*VV + v, 0..1535
        xs[half][c] = x[row * HID + c];
        __syncthreads();
        const float4* xs4 = (const float4*)xs[half];
        const float4* wq4 = (const float4*)(Wq + c * HID);
        const float4* wk4 = (const float4*)(Wk + c * HID);
        const float4* wv4 = (const float4*)(Wv + c * HID);
        float aq = 0.f, ak = 0.f, av = 0.f;
#pragma unroll
        for (int k4 = 0; k4 < HID / 4; ++k4) {
            float4 xv = xs4[k4];
            float4 a = wq4[k4];
            aq += xv.x * a.x + xv.y * a.y + xv.z * a.z + xv.w * a.w;
            float4 bv2 = wk4[k4];
            ak += xv.x * bv2.x + xv.y * bv2.y + xv.z * bv2.z + xv.w * bv2.w;
            float4 cv = wv4[k4];
            av += xv.x * cv.x + xv.y * cv.y + xv.z * cv.z + xv.w * cv.w;
        }
        const int b = row / VV, vi = row - b * VV;
        const int idx = ((b * NH + (c >> 4)) * VV + vi) * HD + (c & 15);
        qh[idx] = aq + bq[c];
        kh[idx] = ak + bk[c];
        vh[idx] = av + bv[c];
    } else {
        const int l = threadIdx.x & 63;
        const int w = (blockIdx.x - QKV_BLOCKS) * 4 + (threadIdx.x >> 6); // 0..8191
        const float4* eg4 = (const float4*)eg;
        const size_t wbase = (size_t)w * (EDGE_ITERS * 64);  // float4 units
#pragma unroll 4
        for (int it = 0; it < EDGE_ITERS; ++it) {
            float4 v = eg4[wbase + it * 64 + l];
            float s = (v.x + v.y) + (v.z + v.w);
            s += __shfl_xor(s, 1);
            s += __shfl_xor(s, 2);
            s += __shfl_xor(s, 4);
            s += __shfl_xor(s, 8);
            s += __shfl_xor(s, 16);
            if ((l & 31) == 0) {
                const int p = w * EDGE_ITERS + it;       // row-pair index
                mask[p * 2 + (l >> 5)] = s * (1.0f / 128.0f);
            }
        }
    }
}

// ---------------------------------------------------------------------------
// Kernel 2: attention, 2 q-rows per wave (halves K/V L2 re-read, 2x FMA ILP).
// ---------------------------------------------------------------------------
__global__ __launch_bounds__(256) void attn_kernel(
    const float* __restrict__ qh, const float* __restrict__ kh,
    const float* __restrict__ vh, const float* __restrict__ mask,
    float* __restrict__ att) {
    __shared__ float sc[4][2][VV];                   // 24 KB
    const int wid  = threadIdx.x >> 6;
    const int lane = threadIdx.x & 63;
    const int gw   = blockIdx.x * 4 + wid;           // bh*384 + pair
    const int pr   = gw % (VV / 2);
    const int bh   = gw / (VV / 2);
    const int b    = bh >> 3, h = bh & 7;
    const int q0i  = pr * 2, q1i = q0i + 1;

    const float4* qp0 = (const float4*)(qh + ((size_t)bh * VV + q0i) * HD);
    const float4 qa0 = qp0[0], qa1 = qp0[1], qa2 = qp0[2], qa3 = qp0[3];
    const float4* qp1 = (const float4*)(qh + ((size_t)bh * VV + q1i) * HD);
    const float4 qb0 = qp1[0], qb1 = qp1[1], qb2 = qp1[2], qb3 = qp1[3];

    const float* mrow0 = mask + ((size_t)b * VV + q0i) * VV;
    const float* mrow1 = mrow0 + VV;
    const float* kbase = kh + (size_t)bh * VV * HD;
    const float* vbase = vh + (size_t)bh * VV * HD;

    float m0 = -INFINITY, m1 = -INFINITY;
#pragma unroll
    for (int t = 0; t < VV / 64; ++t) {
        const int j = lane + 64 * t;
        const float4* kp = (const float4*)(kbase + j * HD);
        float4 k0 = kp[0], k1 = kp[1], k2 = kp[2], k3 = kp[3];
        float d0 = qa0.x * k0.x + qa0.y * k0.y + qa0.z * k0.z + qa0.w * k0.w
                 + qa1.x * k1.x + qa1.y * k1.y + qa1.z * k1.z + qa1.w * k1.w
                 + qa2.x * k2.x + qa2.y * k2.y + qa2.z * k2.z + qa2.w * k2.w
                 + qa3.x * k3.x + qa3.y * k3.y + qa3.z * k3.z + qa3.w * k3.w;
        float d1 = qb0.x * k0.x + qb0.y * k0.y + qb0.z * k0.z + qb0.w * k0.w
                 + qb1.x * k1.x + qb1.y * k1.y + qb1.z * k1.z + qb1.w * k1.w
                 + qb2.x * k2.x + qb2.y * k2.y + qb2.z * k2.z + qb2.w * k2.w
                 + qb3.x * k3.x + qb3.y * k3.y + qb3.z * k3.z + qb3.w * k3.w;
        float s0 = d0 * 0.25f * mrow0[j];
        float s1 = d1 * 0.25f * mrow1[j];
        sc[wid][0][j] = s0;
        sc[wid][1][j] = s1;
        m0 = fmaxf(m0, s0);
        m1 = fmaxf(m1, s1);
    }
#pragma unroll
    for (int off = 1; off < 64; off <<= 1) {
        m0 = fmaxf(m0, __shfl_xor(m0, off));
        m1 = fmaxf(m1, __shfl_xor(m1, off));
    }

    float sum0 = 0.f, sum1 = 0.f;
    float acc0[HD], acc1[HD];
#pragma unroll
    for (int d = 0; d < HD; ++d) { acc0[d] = 0.f; acc1[d] = 0.f; }
#pragma unroll
    for (int t = 0; t < VV / 64; ++t) {
        const int j = lane + 64 * t;
        float e0 = __expf(sc[wid][0][j] - m0);
        float e1 = __expf(sc[wid][1][j] - m1);
        sum0 += e0;
        sum1 += e1;
        const float4* vp = (const float4*)(vbase + j * HD);
        float4 v0 = vp[0], v1 = vp[1], v2 = vp[2], v3 = vp[3];
        acc0[0]  += e0 * v0.x; acc0[1]  += e0 * v0.y; acc0[2]  += e0 * v0.z; acc0[3]  += e0 * v0.w;
        acc0[4]  += e0 * v1.x; acc0[5]  += e0 * v1.y; acc0[6]  += e0 * v1.z; acc0[7]  += e0 * v1.w;
        acc0[8]  += e0 * v2.x; acc0[9]  += e0 * v2.y; acc0[10] += e0 * v2.z; acc0[11] += e0 * v2.w;
        acc0[12] += e0 * v3.x; acc0[13] += e0 * v3.y; acc0[14] += e0 * v3.z; acc0[15] += e0 * v3.w;
        acc1[0]  += e1 * v0.x; acc1[1]  += e1 * v0.y; acc1[2]  += e1 * v0.z; acc1[3]  += e1 * v0.w;
        acc1[4]  += e1 * v1.x; acc1[5]  += e1 * v1.y; acc1[6]  += e1 * v1.z; acc1[7]  += e1 * v1.w;
        acc1[8]  += e1 * v2.x; acc1[9]  += e1 * v2.y; acc1[10] += e1 * v2.z; acc1[11] += e1 * v2.w;
        acc1[12] += e1 * v3.x; acc1[13] += e1 * v3.y; acc1[14] += e1 * v3.z; acc1[15] += e1 * v3.w;
    }
#pragma unroll
    for (int off = 1; off < 64; off <<= 1) {
        sum0 += __shfl_xor(sum0, off);
        sum1 += __shfl_xor(sum1, off);
    }

#pragma unroll
    for (int i = 0; i < 8; ++i) {
        float sa = (lane & 1) ? acc0[i] : acc0[i + 8];
        float ra = __shfl_xor(sa, 1);
        acc0[i] = ((lane & 1) ? acc0[i + 8] : acc0[i]) + ra;
        float sb = (lane & 1) ? acc1[i] : acc1[i + 8];
        float rb = __shfl_xor(sb, 1);
        acc1[i] = ((lane & 1) ? acc1[i + 8] : acc1[i]) + rb;
    }
#pragma unroll
    for (int i = 0; i < 4; ++i) {
        float sa = (lane & 2) ? acc0[i] : acc0[i + 4];
        float ra = __shfl_xor(sa, 2);
        acc0[i] = ((lane & 2) ? acc0[i + 4] : acc0[i]) + ra;
        float sb = (lane & 2) ? acc1[i] : acc1[i + 4];
        float rb = __shfl_xor(sb, 2);
        acc1[i] = ((lane & 2) ? acc1[i + 4] : acc1[i]) + rb;
    }
#pragma unroll
    for (int i = 0; i < 2; ++i) {
        float sa = (lane & 4) ? acc0[i] : acc0[i + 2];
        float ra = __shfl_xor(sa, 4);
        acc0[i] = ((lane & 4) ? acc0[i + 2] : acc0[i]) + ra;
        float sb = (lane & 4) ? acc1[i] : acc1[i + 2];
        float rb = __shfl_xor(sb, 4);
        acc1[i] = ((lane & 4) ? acc1[i + 2] : acc1[i]) + rb;
    }
    {
        float sa = (lane & 8) ? acc0[0] : acc0[1];
        float ra = __shfl_xor(sa, 8);
        acc0[0] = ((lane & 8) ? acc0[1] : acc0[0]) + ra;
        float sb = (lane & 8) ? acc1[0] : acc1[1];
        float rb = __shfl_xor(sb, 8);
        acc1[0] = ((lane & 8) ? acc1[1] : acc1[0]) + rb;
    }
    acc0[0] += __shfl_xor(acc0[0], 16);
    acc0[0] += __shfl_xor(acc0[0], 32);
    acc1[0] += __shfl_xor(acc1[0], 16);
    acc1[0] += __shfl_xor(acc1[0], 32);

    const int d = ((lane & 1) << 3) | ((lane & 2) << 1) | ((lane & 4) >> 1) | ((lane & 8) >> 3);
    if (lane < HD) {
        att[((size_t)b * VV + q0i) * HID + h * HD + d] = acc0[0] / sum0;
        att[((size_t)b * VV + q1i) * HID + h * HD + d] = acc1[0] / sum1;
    }
}

// ---------------------------------------------------------------------------
// Kernel 3: out = att @ Wo^T + bo
// ---------------------------------------------------------------------------
__global__ __launch_bounds__(128) void outproj_kernel(
    const float* __restrict__ att, const float* __restrict__ Wo,
    const float* __restrict__ bo, float* __restrict__ out) {
    const int row = blockIdx.x;
    const int c   = threadIdx.x;
    __shared__ float xs[HID];
    xs[c] = att[row * HID + c];
    __syncthreads();
    const float4* xs4 = (const float4*)xs;
    const float4* wo4 = (const float4*)(Wo + c * HID);
    float a = 0.f;
#pragma unroll
    for (int k4 = 0; k4 < HID / 4; ++k4) {
        float4 xv = xs4[k4];
        float4 wv = wo4[k4];
        a += xv.x * wv.x + xv.y * wv.y + xv.z * wv.z + xv.w * wv.w;
    }
    out[row * HID + c] = a + bo[c];
}

extern "C" void kernel_launch(void* const* d_in, const int* in_sizes, int n_in,
                              void* d_out, int out_size, void* d_ws, size_t ws_size,
                              hipStream_t stream) {
    const float* x  = (const float*)d_in[0];
    const float* eg = (const float*)d_in[1];
    const float* Wq = (const float*)d_in[2];
    const float* bq = (const float*)d_in[3];
    const float* Wk = (const float*)d_in[4];
    const float* bk = (const float*)d_in[5];
    const float* Wv = (const float*)d_in[6];
    const float* bv = (const float*)d_in[7];
    const float* Wo = (const float*)d_in[8];
    const float* bo = (const float*)d_in[9];
    float* out = (float*)d_out;

    float* ws   = (float*)d_ws;
    float* mask = ws;                                        // B*V*V
    float* qh   = mask + (size_t)BB * VV * VV;               // B*V*HID each
    float* kh   = qh + (size_t)BB * VV * HID;
    float* vh   = kh + (size_t)BB * VV * HID;
    float* att  = vh + (size_t)BB * VV * HID;

    hipLaunchKernelGGL(fused_qkv_edgemean, dim3(QKV_BLOCKS + EDGE_BLOCKS), dim3(256), 0, stream,
                       x, eg, Wq, bq, Wk, bk, Wv, bv, qh, kh, vh, mask);
    hipLaunchKernelGGL(attn_kernel, dim3(BB * NH * VV / 8), dim3(256), 0, stream,
                       qh, kh, vh, mask, att);
    hipLaunchKernelGGL(outproj_kernel, dim3(BB * VV), dim3(128), 0, stream,
                       att, Wo, bo, out);
}